// Round 6
// baseline (141.098 us; speedup 1.0000x reference)
//
#include <hip/hip_runtime.h>

// Problem constants
#define S_   16384
#define T_   16384
#define B_   32
#define NEDGES (S_ * 64)       // 1,048,576
#define GP_  512               // producer blocks (2048 edges each)
#define NBKT 512               // buckets of 32 targets
#define TPB  32                // targets per bucket
#define CAP_CELL  16           // slot 0 = header {count}, slots 1..15 = records
#define CAP_SPILL 16           // per-producer spill slots (expected use: 0)
#define CAP_SRT   2560         // bucket records: lambda=2048, +11 sigma

// weight = clip(att,0,1) * 0.9^delay, delay in [0,6). Exact bit-product.
__device__ __forceinline__ float edge_weight(float a, int d) {
  float w = fminf(fmaxf(a, 0.0f), 1.0f);
  float r = (d & 1) ? 0.9f : 1.0f;
  r = (d & 2) ? r * 0.81f   : r;
  r = (d & 4) ? r * 0.6561f : r;
  return w * r;
}

// ---------------------------------------------------------------------------
// K1: transpose 32 sources of spikes + scatter 2048 edges into header cells.
// rec cell (bkt,g): 16 int2 slots; slot0.x = record count, slots 1.. = records
// {meta = tl<<14 | src, w_bits}.
__global__ __launch_bounds__(512) void produce(
    const float* __restrict__ spikes,
    const float* __restrict__ att,
    const int*   __restrict__ tgt,
    const int*   __restrict__ del,
    float* __restrict__ spikesT,
    int2*  __restrict__ rec,
    int*   __restrict__ spillCnt,   // [GP_]
    int2*  __restrict__ spill) {    // [GP_][CAP_SPILL] {bkt<<19|tl<<14|src, w}
  __shared__ float tile[32][33];
  __shared__ int   cur[NBKT];
  __shared__ int   scur;
  const int g   = blockIdx.x;
  const int tid = threadIdx.x;

  cur[tid] = 1;                     // slot 0 reserved for header
  if (tid == 0) scur = 0;

  // transpose sources [g*32, g*32+32)
  const int s0 = g * 32;
  {
    const int x = tid & 31;         // source offset
    const int y = tid >> 5;         // batch 0..15
    tile[x][y]      = spikes[(size_t)y        * S_ + s0 + x];
    tile[x][y + 16] = spikes[(size_t)(y + 16) * S_ + s0 + x];
    __syncthreads();                // also publishes cur[]/scur init
    const int b = tid & 31;
    const int j = tid >> 5;         // 0..15
    spikesT[(size_t)(s0 + j)      * 32 + b] = tile[j][b];
    spikesT[(size_t)(s0 + j + 16) * 32 + b] = tile[j + 16][b];
  }

  // 4 edges per thread
  const int e4  = g * 512 + tid;
  int4   t = reinterpret_cast<const int4*>(tgt)[e4];
  float4 a = reinterpret_cast<const float4*>(att)[e4];
  int4   d = reinterpret_cast<const int4*>(del)[e4];
  const int src = (e4 * 4) >> 6;    // 4 consecutive edges share one source

#define EMIT(TV, AV, DV)                                                      \
  {                                                                           \
    const int bkt = (TV) >> 5;                                                \
    const int tl  = (TV) & 31;                                                \
    const int wb  = __float_as_int(edge_weight((AV), (DV)));                  \
    int slot = __hip_atomic_fetch_add(&cur[bkt], 1, __ATOMIC_RELAXED,         \
                                      __HIP_MEMORY_SCOPE_WORKGROUP);          \
    if (slot < CAP_CELL) {                                                    \
      rec[(((size_t)((bkt << 9) | g)) << 4) + slot] =                         \
          make_int2((tl << 14) | src, wb);                                    \
    } else {                                                                  \
      int sp = __hip_atomic_fetch_add(&scur, 1, __ATOMIC_RELAXED,             \
                                      __HIP_MEMORY_SCOPE_WORKGROUP);          \
      if (sp < CAP_SPILL)                                                     \
        spill[g * CAP_SPILL + sp] =                                           \
            make_int2((bkt << 19) | (tl << 14) | src, wb);                    \
    }                                                                         \
  }
  EMIT(t.x, a.x, d.x)
  EMIT(t.y, a.y, d.y)
  EMIT(t.z, a.z, d.z)
  EMIT(t.w, a.w, d.w)
#undef EMIT

  __syncthreads();
  // headers: cell (bkt=tid, g) count, written into the line we just filled
  rec[((size_t)((tid << 9) | g)) << 4] = make_int2(min(cur[tid] - 1, 15), 0);
  if (tid == 0) spillCnt[g] = min(scur, CAP_SPILL);
}

// ---------------------------------------------------------------------------
// K2: per-bucket fine sort (32 bins, shuffle scan) + atomic-free gather.
// 512 threads; thread = one producer cell; half-wave hw owns targets hw, hw+16.
__global__ __launch_bounds__(512) void consume(
    const int2* __restrict__ rec,
    const int*  __restrict__ spillCnt,
    const int2* __restrict__ spill,
    const float* __restrict__ spikesT,
    float* __restrict__ out) {
  __shared__ int2  srt[CAP_SRT];        // 20 KB
  __shared__ float otile[TPB][33];      // 4.2 KB
  __shared__ int   h32[TPB], ofs[TPB + 1], cur32[TPB];
  __shared__ int   spill_any;

  const int k   = blockIdx.x;           // bucket: targets [k*32, k*32+32)
  const int tid = threadIdx.x;
  const int b   = tid & 31;
  const int hw  = tid >> 5;             // 0..15

  if (tid < TPB) h32[tid] = 0;
  if (tid == 0)  spill_any = 0;
  const int myspill = spillCnt[tid];    // GP_ == blockDim
  __syncthreads();
  if (myspill)
    __hip_atomic_fetch_add(&spill_any, myspill, __ATOMIC_RELAXED,
                           __HIP_MEMORY_SCOPE_WORKGROUP);

  // load my cell (bkt k, producer tid): slots 0..7 (64 B, coalesced)
  const int4* cp = reinterpret_cast<const int4*>(
      rec + (((size_t)((k << 9) | tid)) << 4));
  int4 c0 = cp[0], c1 = cp[1], c2 = cp[2], c3 = cp[3];
  const int n = min(c0.x, 15);
  int2 lo[7] = {{c0.z, c0.w}, {c1.x, c1.y}, {c1.z, c1.w},
                {c2.x, c2.y}, {c2.z, c2.w}, {c3.x, c3.y}, {c3.z, c3.w}};
  int2 hi[8];
  if (n > 7) {                          // P ~ 5% (lambda = 4)
    int4 c4 = cp[4], c5 = cp[5], c6 = cp[6], c7 = cp[7];
    hi[0] = {c4.x, c4.y}; hi[1] = {c4.z, c4.w};
    hi[2] = {c5.x, c5.y}; hi[3] = {c5.z, c5.w};
    hi[4] = {c6.x, c6.y}; hi[5] = {c6.z, c6.w};
    hi[6] = {c7.x, c7.y}; hi[7] = {c7.z, c7.w};
  }

  // fine histogram (32 bins = 32 banks)
#pragma unroll
  for (int j = 0; j < 7; ++j)
    if (j < n)
      __hip_atomic_fetch_add(&h32[(lo[j].x >> 14) & 31], 1, __ATOMIC_RELAXED,
                             __HIP_MEMORY_SCOPE_WORKGROUP);
  if (n > 7) {
#pragma unroll
    for (int j = 0; j < 8; ++j)
      if (7 + j < n)
        __hip_atomic_fetch_add(&h32[(hi[j].x >> 14) & 31], 1, __ATOMIC_RELAXED,
                               __HIP_MEMORY_SCOPE_WORKGROUP);
  }
  __syncthreads();

  // exclusive scan of 32 bins via wave shuffles (wave 0 only)
  if (tid < 32) {
    int v = h32[tid];
    const int orig = v;
#pragma unroll
    for (int off = 1; off < 32; off <<= 1) {
      int u = __shfl_up(v, off);
      if (tid >= off) v += u;
    }
    ofs[tid]   = v - orig;
    cur32[tid] = v - orig;
    if (tid == 31) ofs[32] = v;
  }
  __syncthreads();

  // rank + scatter into srt
#pragma unroll
  for (int j = 0; j < 7; ++j)
    if (j < n) {
      int2 r = lo[j];
      int p = __hip_atomic_fetch_add(&cur32[(r.x >> 14) & 31], 1,
                                     __ATOMIC_RELAXED,
                                     __HIP_MEMORY_SCOPE_WORKGROUP);
      if (p < CAP_SRT) srt[p] = make_int2(r.x & 0x3FFF, r.y);
    }
  if (n > 7) {
#pragma unroll
    for (int j = 0; j < 8; ++j)
      if (7 + j < n) {
        int2 r = hi[j];
        int p = __hip_atomic_fetch_add(&cur32[(r.x >> 14) & 31], 1,
                                       __ATOMIC_RELAXED,
                                       __HIP_MEMORY_SCOPE_WORKGROUP);
        if (p < CAP_SRT) srt[p] = make_int2(r.x & 0x3FFF, r.y);
      }
  }
  __syncthreads();

  // gather: half-wave hw owns targets hw (acc0) and hw+16 (acc1); lane = batch
  float acc0 = 0.f, acc1 = 0.f;
  {
    int e        = ofs[hw];
    const int e1 = ofs[hw + 1];
    for (; e + 2 <= e1; e += 2) {
      int2 r0 = srt[e], r1 = srt[e + 1];
      acc0 = fmaf(__int_as_float(r0.y), spikesT[(size_t)r0.x * 32 + b], acc0);
      acc0 = fmaf(__int_as_float(r1.y), spikesT[(size_t)r1.x * 32 + b], acc0);
    }
    if (e < e1) {
      int2 r = srt[e];
      acc0 = fmaf(__int_as_float(r.y), spikesT[(size_t)r.x * 32 + b], acc0);
    }
  }
  {
    int e        = ofs[hw + 16];
    const int e1 = ofs[hw + 17];
    for (; e + 2 <= e1; e += 2) {
      int2 r0 = srt[e], r1 = srt[e + 1];
      acc1 = fmaf(__int_as_float(r0.y), spikesT[(size_t)r0.x * 32 + b], acc1);
      acc1 = fmaf(__int_as_float(r1.y), spikesT[(size_t)r1.x * 32 + b], acc1);
    }
    if (e < e1) {
      int2 r = srt[e];
      acc1 = fmaf(__int_as_float(r.y), spikesT[(size_t)r.x * 32 + b], acc1);
    }
  }

  // spill entries (expected: none)
  if (spill_any > 0) {
    for (int g2 = 0; g2 < GP_; ++g2) {
      const int ns = spillCnt[g2];
      for (int j = 0; j < ns; ++j) {
        int2 e = spill[g2 * CAP_SPILL + j];
        if ((e.x >> 19) != k) continue;
        const int tl = (e.x >> 14) & 31;
        const float v = __int_as_float(e.y) *
                        spikesT[(size_t)(e.x & 0x3FFF) * 32 + b];
        if (tl == hw)           acc0 += v;
        else if (tl == hw + 16) acc1 += v;
      }
    }
  }

  // transpose 32x32 tile and write out coalesced
  otile[hw][b]      = acc0;
  otile[hw + 16][b] = acc1;
  __syncthreads();
  const int bb = tid >> 4;              // batch 0..31
  const int cc = (tid & 15) * 2;        // target pair
  float2 o2 = make_float2(otile[cc][bb], otile[cc + 1][bb]);
  *reinterpret_cast<float2*>(&out[(size_t)bb * T_ + k * 32 + cc]) = o2;
}

// ---------------------------------------------------------------------------
__global__ void zero_floats(float* __restrict__ p, int n) {
  int i = blockIdx.x * blockDim.x + threadIdx.x;
  if (i < n) p[i] = 0.0f;
}

// Emergency fallback (tiny ws): direct global atomics, weights inline.
__global__ void naive_kernel(const float* __restrict__ spikes,
                             const float* __restrict__ att,
                             const int*   __restrict__ tgt,
                             const int*   __restrict__ del,
                             float*       __restrict__ out) {
  int i = blockIdx.x * blockDim.x + threadIdx.x;
  if (i >= NEDGES) return;
  int   s = i >> 6;
  int   t = tgt[i];
  float w = edge_weight(att[i], del[i]);
  for (int b = 0; b < B_; ++b)
    unsafeAtomicAdd(&out[(size_t)b * T_ + t], w * spikes[(size_t)b * S_ + s]);
}

// ---------------------------------------------------------------------------
extern "C" void kernel_launch(void* const* d_in, const int* in_sizes, int n_in,
                              void* d_out, int out_size, void* d_ws, size_t ws_size,
                              hipStream_t stream) {
  const float* spikes = (const float*)d_in[0];
  const float* att    = (const float*)d_in[1];
  const int*   tgt    = (const int*)d_in[2];
  const int*   del    = (const int*)d_in[3];
  float*       out    = (float*)d_out;

  const size_t spikesT_bytes = (size_t)S_ * B_ * sizeof(float);              // 2 MB
  const size_t rec_bytes     = (size_t)NBKT * GP_ * CAP_CELL * sizeof(int2); // 32 MB
  const size_t spillc_bytes  = (size_t)GP_ * sizeof(int);
  const size_t spill_bytes   = (size_t)GP_ * CAP_SPILL * sizeof(int2);
  const size_t need = spikesT_bytes + rec_bytes + spillc_bytes + spill_bytes + 64;

  if (ws_size < need) {
    zero_floats<<<(B_ * T_ + 255) / 256, 256, 0, stream>>>(out, B_ * T_);
    naive_kernel<<<(NEDGES + 255) / 256, 256, 0, stream>>>(spikes, att, tgt, del, out);
    return;
  }

  char* p = (char*)d_ws;
  float* spikesT  = (float*)p;  p += spikesT_bytes;
  int2*  rec      = (int2*)p;   p += rec_bytes;
  int*   spillCnt = (int*)p;    p += spillc_bytes;
  int2*  spill    = (int2*)p;

  produce<<<GP_, 512, 0, stream>>>(spikes, att, tgt, del,
                                   spikesT, rec, spillCnt, spill);
  consume<<<NBKT, 512, 0, stream>>>(rec, spillCnt, spill, spikesT, out);
}

// Round 7
// 93.867 us; speedup vs baseline: 1.5032x; 1.5032x over previous
//
#include <hip/hip_runtime.h>

// Problem constants
#define S_   16384
#define T_   16384
#define B_   32
#define NEDGES (S_ * 64)       // 1,048,576
#define GP_  256               // producer blocks, 4096 edges each
#define EPG  4096              // edges per producer block
#define NBKT 512               // buckets of 32 targets
#define TPB  32                // targets per bucket
#define CAP_SRT 2560           // per-bucket records: lambda=2048, +11 sigma

// weight = clip(att,0,1) * 0.9^delay, delay in [0,6). Exact bit-product.
__device__ __forceinline__ float edge_weight(float a, int d) {
  float w = fminf(fmaxf(a, 0.0f), 1.0f);
  float r = (d & 1) ? 0.9f : 1.0f;
  r = (d & 2) ? r * 0.81f   : r;
  r = (d & 4) ? r * 0.6561f : r;
  return w * r;
}

// ---------------------------------------------------------------------------
// K1: transpose 64 sources of spikes + LDS counting-sort of 4096 edges by
// bucket + ONE contiguous 32 KB flush (full lines, no padding, no spill).
// rec[g][i], i in [0,4096): records {meta = tl<<14 | src, w_bits} grouped by
// bucket; ofse[g][bkt] = end<<16 | start (within-block slice bounds).
__global__ __launch_bounds__(1024) void produce(
    const float* __restrict__ spikes,
    const float* __restrict__ att,
    const int*   __restrict__ tgt,
    const int*   __restrict__ del,
    float*        __restrict__ spikesT,
    int2*         __restrict__ rec,
    unsigned int* __restrict__ ofse) {
  __shared__ float tile[64][33];        // 8.4 KB
  __shared__ int4  sbuf4[EPG / 2];      // 32 KB: 4096 int2 records
  __shared__ int   cnt5[NBKT], cur5[NBKT], sofs5[NBKT];
  __shared__ int   wtot[8];
  int2* buf = (int2*)sbuf4;

  const int g   = blockIdx.x;
  const int tid = threadIdx.x;
  if (tid < NBKT) cnt5[tid] = 0;

  // -- transpose sources [g*64, g*64+64): load half
  const int s0 = g * 64;
  {
    const int x = tid & 63, y = tid >> 6;       // y 0..15
    tile[x][y]      = spikes[(size_t)y        * S_ + s0 + x];
    tile[x][y + 16] = spikes[(size_t)(y + 16) * S_ + s0 + x];
  }

  // -- load my 4 edges (kept in registers across all phases)
  const int e4  = g * 1024 + tid;
  int4   t = reinterpret_cast<const int4*>(tgt)[e4];
  float4 a = reinterpret_cast<const float4*>(att)[e4];
  int4   d = reinterpret_cast<const int4*>(del)[e4];
  const int src = (e4 * 4) >> 6;                // 4 consecutive edges: 1 source

  __syncthreads();                              // cnt5 init + tile visible

  // -- transpose write
  {
    const int b = tid & 31, j = tid >> 5;       // j 0..31
    spikesT[(size_t)(s0 + j)      * 32 + b] = tile[j][b];
    spikesT[(size_t)(s0 + j + 32) * 32 + b] = tile[j + 32][b];
  }

  // -- pass 1: bucket histogram (ds_add, no return needed)
  const int bk0 = t.x >> 5, bk1 = t.y >> 5, bk2 = t.z >> 5, bk3 = t.w >> 5;
  __hip_atomic_fetch_add(&cnt5[bk0], 1, __ATOMIC_RELAXED, __HIP_MEMORY_SCOPE_WORKGROUP);
  __hip_atomic_fetch_add(&cnt5[bk1], 1, __ATOMIC_RELAXED, __HIP_MEMORY_SCOPE_WORKGROUP);
  __hip_atomic_fetch_add(&cnt5[bk2], 1, __ATOMIC_RELAXED, __HIP_MEMORY_SCOPE_WORKGROUP);
  __hip_atomic_fetch_add(&cnt5[bk3], 1, __ATOMIC_RELAXED, __HIP_MEMORY_SCOPE_WORKGROUP);
  __syncthreads();

  // -- exclusive scan of 512 bins: waves 0..7 shuffle-scan 64 each + combine
  int v = 0, incl = 0;
  if (tid < NBKT) {
    v = cnt5[tid];
    incl = v;
#pragma unroll
    for (int off = 1; off < 64; off <<= 1) {
      int u = __shfl_up(incl, off);
      if ((tid & 63) >= off) incl += u;
    }
    if ((tid & 63) == 63) wtot[tid >> 6] = incl;
  }
  __syncthreads();
  if (tid < NBKT) {
    int base = 0;
    const int wv = tid >> 6;
    for (int i = 0; i < wv; ++i) base += wtot[i];
    const int start = base + incl - v;
    sofs5[tid] = start;
    cur5[tid]  = start;
  }
  __syncthreads();

  // -- pass 2: weight + place into LDS at bucket cursor (exact, no overflow)
#define PUT(BK, TL, AV, DV)                                                   \
  {                                                                           \
    int p = __hip_atomic_fetch_add(&cur5[BK], 1, __ATOMIC_RELAXED,            \
                                   __HIP_MEMORY_SCOPE_WORKGROUP);             \
    buf[p] = make_int2(((TL) << 14) | src,                                    \
                       __float_as_int(edge_weight((AV), (DV))));              \
  }
  PUT(bk0, t.x & 31, a.x, d.x)
  PUT(bk1, t.y & 31, a.y, d.y)
  PUT(bk2, t.z & 31, a.z, d.z)
  PUT(bk3, t.w & 31, a.w, d.w)
#undef PUT
  __syncthreads();

  // -- flush: one contiguous 32 KB stream of full lines (int4 x2 per thread)
  int4* recO = reinterpret_cast<int4*>(rec) + (size_t)g * (EPG / 2);
  recO[tid]        = sbuf4[tid];
  recO[tid + 1024] = sbuf4[tid + 1024];
  if (tid < NBKT)
    ofse[(size_t)g * NBKT + tid] =
        ((unsigned)cur5[tid] << 16) | (unsigned)sofs5[tid];   // coalesced
}

// ---------------------------------------------------------------------------
// K2: bucket k gathers its 256 slices (dense coalesced lines), LDS-stages,
// fine-sorts by target (shuffle scans, LDS cursors), register gather, direct
// coalesced out write. 512 blocks x 512 threads = 2 blocks/CU.
__global__ __launch_bounds__(512) void consume(
    const int2*  __restrict__ rec,
    const unsigned int* __restrict__ ofse,
    const float* __restrict__ spikesT,
    float* __restrict__ out) {
  __shared__ int2  raw[CAP_SRT];        // 20 KB unsorted stage
  __shared__ int2  srt[CAP_SRT];        // 20 KB target-sorted
  __shared__ float otile[TPB][33];      // 4.2 KB
  __shared__ unsigned sse[GP_];
  __shared__ int   sstart[GP_];
  __shared__ int   wtot4[4];
  __shared__ int   h32[TPB], ofs[TPB + 1], cur32[TPB];

  const int k   = blockIdx.x;
  const int tid = threadIdx.x;
  const int b   = tid & 31;
  const int hw  = tid >> 5;             // 0..15

  if (tid < TPB) h32[tid] = 0;
  if (tid < GP_) sse[tid] = ofse[(size_t)tid * NBKT + k];   // strided, 1 instr
  __syncthreads();

  // scan256 of slice counts -> staging offsets + total
  int v = 0, incl = 0;
  if (tid < GP_) {
    const unsigned u = sse[tid];
    v = (int)(u >> 16) - (int)(u & 0xFFFF);
    incl = v;
#pragma unroll
    for (int off = 1; off < 64; off <<= 1) {
      int uu = __shfl_up(incl, off);
      if ((tid & 63) >= off) incl += uu;
    }
    if ((tid & 63) == 63) wtot4[tid >> 6] = incl;
  }
  __syncthreads();
  if (tid < GP_) {
    int base = 0;
    const int wv = tid >> 6;
    for (int i = 0; i < wv; ++i) base += wtot4[i];
    sstart[tid] = base + incl - v;
  }
  __syncthreads();
  const int total = min(wtot4[0] + wtot4[1] + wtot4[2] + wtot4[3], CAP_SRT);

  // pass 1: read slices (half-wave coalesced), histogram + stage into raw
  for (int it = 0; it < 16; ++it) {
    const int g = hw + it * 16;
    const unsigned u = sse[g];
    const int st = (int)(u & 0xFFFF);
    const int n  = (int)(u >> 16) - st;
    const int2* slice = rec + (size_t)g * EPG + st;
    const int lbase = sstart[g];
    for (int j = b; j < n; j += 32) {
      int2 r = slice[j];
      __hip_atomic_fetch_add(&h32[(r.x >> 14) & 31], 1, __ATOMIC_RELAXED,
                             __HIP_MEMORY_SCOPE_WORKGROUP);
      const int idx = lbase + j;
      if (idx < CAP_SRT) raw[idx] = r;
    }
  }
  __syncthreads();

  // scan32 of target bins (wave 0)
  if (tid < 32) {
    int vv = h32[tid], ii = vv;
#pragma unroll
    for (int off = 1; off < 32; off <<= 1) {
      int uu = __shfl_up(ii, off);
      if (tid >= off) ii += uu;
    }
    ofs[tid]   = ii - vv;
    cur32[tid] = ii - vv;
    if (tid == 31) ofs[32] = ii;
  }
  __syncthreads();

  // pass 2: rank + scatter raw -> srt (LDS only)
  for (int i = tid; i < total; i += 512) {
    int2 r = raw[i];
    int p = __hip_atomic_fetch_add(&cur32[(r.x >> 14) & 31], 1,
                                   __ATOMIC_RELAXED,
                                   __HIP_MEMORY_SCOPE_WORKGROUP);
    if (p < CAP_SRT) srt[p] = r;
  }
  __syncthreads();

  // gather: half-wave hw owns targets hw (acc0), hw+16 (acc1); lane = batch
  float acc0 = 0.f, acc1 = 0.f;
  {
    int e        = ofs[hw];
    const int e1 = min(ofs[hw + 1], total);
    for (; e + 4 <= e1; e += 4) {
      int2 r0 = srt[e], r1 = srt[e + 1], r2 = srt[e + 2], r3 = srt[e + 3];
      float s0 = spikesT[(size_t)(r0.x & 0x3FFF) * 32 + b];
      float s1 = spikesT[(size_t)(r1.x & 0x3FFF) * 32 + b];
      float s2 = spikesT[(size_t)(r2.x & 0x3FFF) * 32 + b];
      float s3 = spikesT[(size_t)(r3.x & 0x3FFF) * 32 + b];
      acc0 = fmaf(__int_as_float(r0.y), s0, acc0);
      acc0 = fmaf(__int_as_float(r1.y), s1, acc0);
      acc0 = fmaf(__int_as_float(r2.y), s2, acc0);
      acc0 = fmaf(__int_as_float(r3.y), s3, acc0);
    }
    for (; e < e1; ++e) {
      int2 r = srt[e];
      acc0 = fmaf(__int_as_float(r.y), spikesT[(size_t)(r.x & 0x3FFF) * 32 + b], acc0);
    }
  }
  {
    int e        = ofs[hw + 16];
    const int e1 = min(ofs[hw + 17], total);
    for (; e + 4 <= e1; e += 4) {
      int2 r0 = srt[e], r1 = srt[e + 1], r2 = srt[e + 2], r3 = srt[e + 3];
      float s0 = spikesT[(size_t)(r0.x & 0x3FFF) * 32 + b];
      float s1 = spikesT[(size_t)(r1.x & 0x3FFF) * 32 + b];
      float s2 = spikesT[(size_t)(r2.x & 0x3FFF) * 32 + b];
      float s3 = spikesT[(size_t)(r3.x & 0x3FFF) * 32 + b];
      acc1 = fmaf(__int_as_float(r0.y), s0, acc1);
      acc1 = fmaf(__int_as_float(r1.y), s1, acc1);
      acc1 = fmaf(__int_as_float(r2.y), s2, acc1);
      acc1 = fmaf(__int_as_float(r3.y), s3, acc1);
    }
    for (; e < e1; ++e) {
      int2 r = srt[e];
      acc1 = fmaf(__int_as_float(r.y), spikesT[(size_t)(r.x & 0x3FFF) * 32 + b], acc1);
    }
  }

  // transpose 32x32 tile and write out coalesced
  otile[hw][b]      = acc0;
  otile[hw + 16][b] = acc1;
  __syncthreads();
  const int bb = tid >> 4;              // batch 0..31
  const int cc = (tid & 15) * 2;        // target pair
  float2 o2 = make_float2(otile[cc][bb], otile[cc + 1][bb]);
  *reinterpret_cast<float2*>(&out[(size_t)bb * T_ + k * 32 + cc]) = o2;
}

// ---------------------------------------------------------------------------
__global__ void zero_floats(float* __restrict__ p, int n) {
  int i = blockIdx.x * blockDim.x + threadIdx.x;
  if (i < n) p[i] = 0.0f;
}

// Emergency fallback (tiny ws): direct global atomics, weights inline.
__global__ void naive_kernel(const float* __restrict__ spikes,
                             const float* __restrict__ att,
                             const int*   __restrict__ tgt,
                             const int*   __restrict__ del,
                             float*       __restrict__ out) {
  int i = blockIdx.x * blockDim.x + threadIdx.x;
  if (i >= NEDGES) return;
  int   s = i >> 6;
  int   t = tgt[i];
  float w = edge_weight(att[i], del[i]);
  for (int b = 0; b < B_; ++b)
    unsafeAtomicAdd(&out[(size_t)b * T_ + t], w * spikes[(size_t)b * S_ + s]);
}

// ---------------------------------------------------------------------------
extern "C" void kernel_launch(void* const* d_in, const int* in_sizes, int n_in,
                              void* d_out, int out_size, void* d_ws, size_t ws_size,
                              hipStream_t stream) {
  const float* spikes = (const float*)d_in[0];
  const float* att    = (const float*)d_in[1];
  const int*   tgt    = (const int*)d_in[2];
  const int*   del    = (const int*)d_in[3];
  float*       out    = (float*)d_out;

  const size_t spikesT_bytes = (size_t)S_ * B_ * sizeof(float);         // 2 MB
  const size_t rec_bytes     = (size_t)NEDGES * sizeof(int2);           // 8 MB
  const size_t ofse_bytes    = (size_t)GP_ * NBKT * sizeof(unsigned);   // 512 KB
  const size_t need = spikesT_bytes + rec_bytes + ofse_bytes + 64;

  if (ws_size < need) {
    zero_floats<<<(B_ * T_ + 255) / 256, 256, 0, stream>>>(out, B_ * T_);
    naive_kernel<<<(NEDGES + 255) / 256, 256, 0, stream>>>(spikes, att, tgt, del, out);
    return;
  }

  char* p = (char*)d_ws;
  float*        spikesT = (float*)p;        p += spikesT_bytes;
  int2*         rec     = (int2*)p;         p += rec_bytes;
  unsigned int* ofse    = (unsigned int*)p;

  produce<<<GP_, 1024, 0, stream>>>(spikes, att, tgt, del, spikesT, rec, ofse);
  consume<<<NBKT, 512, 0, stream>>>(rec, ofse, spikesT, out);
}